// Round 6
// baseline (686.861 us; speedup 1.0000x reference)
//
#include <hip/hip_runtime.h>

// MyRNN: B=128, T=80, E=100, V=10000, U=512
// 8 clusters x 32 member-blocks, formed DYNAMICALLY by physical XCD
// (s_getreg HW_REG_XCC_ID + atomic slot grab): with ~156KB LDS -> 1 block/CU,
// grid 256 fills all CUs, so each XCD hosts exactly 32 blocks -> a cluster's
// members share one L2 BY CONSTRUCTION. Cluster c owns batch rows
// [16c,16c+16); member m owns cols [16m,16m+16) of rk0/rk1/k1 (LDS, hi/lo).
// R1-R6: MALL data-path protocol variants pinned at 5.5-7us/exchange.
// R7 (745us): data on XCD L2 (plain stores + sc0 gathers); MALL atomic ctr.
// R9 (588us): per-member MALL flags -> parallel posts, wave-parallel poll.
// R8/R10: plain-store flags not promptly pollable (store-side lag). HW fact.
// R11 (1445us): global atomics are MEMORY-SIDE, write through to HBM. HW
//   fact. No XCD-L2-local signaling primitive exists; MALL RT is the floor.
// R12 (572us): R9 + sE-overlap + w0-poll + 128B flag lines. Post-mortem:
//   protocol residual 2.65us/exchange = MALL latency + BARRIER-LOCKSTEP SKEW
//   (whole block max-synced over 32 members 2x/step; zero work in the
//   post->poll window to absorb jitter).
// R13: WAVE-AUTONOMOUS DUAL STREAMS. Batch rows are independent recurrences:
//   wave g owns rows [g*8, g*8+8) end-to-end; NO __syncthreads in the main
//   loop. Exchange-independent work (sE stage + x@k0) sits inside the
//   post->poll dependency window; 16KB gathers halve the per-sync L2 burst;
//   each CU runs two streams so spin overlaps compute. MFMA A-rows 8-15
//   duplicate rows 0-7 (read m&7), outputs of those rows not stored (MFMA
//   has no cross-row mixing -> exact). Primitives all R9/R12-proven.
//   Deadlock-free: monotonic per-(member,group) flags, no barriers in loop.
//   WAR-free: posting 2t+1 implies the poster's h-gather completed.

typedef __attribute__((ext_vector_type(8))) short short8;
typedef __attribute__((ext_vector_type(4))) float f32x4;

#define MFMA16(a,b,c) __builtin_amdgcn_mfma_f32_16x16x32_bf16(a,b,c,0,0,0)
#define LOAD_RLX(p)    __hip_atomic_load((p), __ATOMIC_RELAXED, __HIP_MEMORY_SCOPE_AGENT)
#define STORE_RLX(p,v) __hip_atomic_store((p), (v), __ATOMIC_RELAXED, __HIP_MEMORY_SCOPE_AGENT)
#define ADD_RLX(p,v)   __hip_atomic_fetch_add((p), (v), __ATOMIC_RELAXED, __HIP_MEMORY_SCOPE_AGENT)

__device__ __forceinline__ short f2bf(float v){
  unsigned u = __float_as_uint(v);
  u = (u + 0x7fffu + ((u >> 16) & 1u)) >> 16;   // RNE to bf16
  return (short)u;
}
__device__ __forceinline__ float bf2f(short s){
  return __uint_as_float(((unsigned)(unsigned short)s) << 16);
}
__device__ __forceinline__ float fast_tanh(float x){
  x = fminf(15.f, fmaxf(-15.f, x));
  float e = __expf(2.f * x);
  return (e - 1.f) * __builtin_amdgcn_rcpf(e + 1.f);
}

__launch_bounds__(128, 1)
__global__ void rnn_kernel(const int* __restrict__ tokens,
                           const float* __restrict__ emb,
                           const float* __restrict__ k0,
                           const float* __restrict__ rk0,
                           const float* __restrict__ b0,
                           const float* __restrict__ k1,
                           const float* __restrict__ rk1,
                           const float* __restrict__ b1,
                           const float* __restrict__ wd,
                           const float* __restrict__ bd,
                           float* __restrict__ out,
                           char* __restrict__ ws)
{
  constexpr int T = 80, E = 100, U = 512;
  const int tid  = threadIdx.x;
  const int g    = tid >> 6;          // wave id == row-group id (0/1)
  const int lane = tid & 63;
  const int m    = lane & 15;         // A-row (dup m&7) / B,C col
  const int q    = lane >> 4;         // quad 0..3 (C rows q*4..q*4+3)
  const int m7   = m & 7;

  __shared__ __align__(16) short sW[6][16][520];    // rk0 hi/lo, rk1 hi/lo, k1 hi/lo : [col][k]
  __shared__ __align__(16) short sH[2][2][8][520];  // per-group h/h0 staging hi,lo : [g][hl][row][k]
  __shared__ __align__(16) short sE[2][2][8][136];  // per-group emb rows hi,lo (K padded to 128)
  __shared__ __align__(16) short sK0[2][16][136];   // k0 slice hi,lo : [col][k] (padded)
  __shared__ int   sTok[16][80];
  __shared__ float sB0[16], sB1[16];
  __shared__ int   sReg[2];

  // ws layout: regCnt@512 (MALL), flags@4096 (256 members x 128B line, group
  // halves at 64B) .. 36864, exchange data @ 40960 (same footprint as R12).
  int*      regCnt = (int*)(ws + 512);
  int*      flags  = (int*)(ws + 4096);
  unsigned* hPk    = (unsigned*)(ws + 40960);       // h  packed (hi<<16|lo), [128][512]
  unsigned* h0Pk   = hPk + 128*U;                   // h0 packed

  // -------- dynamic cluster formation: cluster id = physical XCD --------
  int xcc;
  asm volatile("s_getreg_b32 %0, hwreg(HW_REG_XCC_ID)" : "=s"(xcc));
  if (tid == 0){
    int slot = ADD_RLX(regCnt + (xcc & 7)*16, 1);  // 0..31 within this XCD
    sReg[0] = xcc & 7;
    sReg[1] = slot;
  }
  __syncthreads();
  const int cl  = sReg[0];
  const int mem = sReg[1];
  int* const myFlag   = flags + (cl*32 + mem)*32 + g*16;          // this (member,group)
  int* const pollAddr = flags + (cl*32 + (lane & 31))*32 + g*16;  // lane -> member, same group

  // ---------------- prologue: stationary weights -> LDS ----------------
  const float* mats[3] = { rk0, rk1, k1 };
  for (int mi = 0; mi < 3; ++mi){
    const float* G = mats[mi];
    for (int i = tid; i < 16*U; i += 128){
      int k = i >> 4, c = i & 15;
      float v  = G[k*U + mem*16 + c];
      short hi = f2bf(v);
      short lo = f2bf(v - bf2f(hi));
      sW[2*mi+0][c][k] = hi;
      sW[2*mi+1][c][k] = lo;
    }
  }
  for (int i = tid; i < 2*2*8*136; i += 128) ((short*)sE)[i]  = 0;
  for (int i = tid; i < 2*16*136;  i += 128) ((short*)sK0)[i] = 0;
  __syncthreads();
  for (int i = tid; i < 16*E; i += 128){
    int e = i >> 4, c = i & 15;
    float v  = k0[e*U + mem*16 + c];
    short hi = f2bf(v);
    short lo = f2bf(v - bf2f(hi));
    sK0[0][c][e] = hi; sK0[1][c][e] = lo;
  }
  for (int i = tid; i < 16*T; i += 128){
    int r = i / T, t = i - r*T;
    sTok[r][t] = tokens[(cl*16 + r)*T + t];
  }
  if (tid < 16){ sB0[tid] = b0[mem*16 + tid]; sB1[tid] = b1[mem*16 + tid]; }
  __syncthreads();
  // -------- after this point: NO __syncthreads. Waves are autonomous. ----

  short (*sHg)[8][520] = sH[g];
  short (*sEg)[8][136] = sE[g];
  unsigned* const hRow0  = hPk  + (cl*16 + g*8)*U;   // this group's 8 rows
  unsigned* const h0Row0 = h0Pk + (cl*16 + g*8)*U;

  // post: drain this wave's data stores (vmcnt ack), then lane0 agent-stores
  // the round id to this (member,group) MALL flag word (R9-proven path).
  auto post = [&](int val){
    asm volatile("s_waitcnt vmcnt(0)" ::: "memory");
    if (lane == 0) STORE_RLX(myFlag, val);
  };
  // wave-parallel poll: lanes watch member (lane&31)'s group-g flag.
  auto pollFlags = [&](int target){
    while (__any(LOAD_RLX(pollAddr) < target)) {}
  };
  // group gather: 8 rows x 512 packed u32 = 16KB; 16 dwordx4/lane, sc0.
  auto gather = [&](const unsigned* srcRow0){
    const uint4* s = (const uint4*)srcRow0;           // 1024 uint4
    uint4 r[16];
    #pragma unroll
    for (int j = 0; j < 16; ++j)
      asm volatile("global_load_dwordx4 %0, %1, off sc0"
                   : "=v"(r[j]) : "v"(&s[j*64 + lane]));
    asm volatile("s_waitcnt vmcnt(0)" ::: "memory");
    #pragma unroll
    for (int j = 0; j < 16; ++j){
      int i = j*64 + lane, row = i >> 7, c = (i & 127) * 4;
      unsigned h0 = (r[j].x >> 16)     | (r[j].y & 0xffff0000u);
      unsigned h1 = (r[j].z >> 16)     | (r[j].w & 0xffff0000u);
      unsigned l0 = (r[j].x & 0xffffu) | (r[j].y << 16);
      unsigned l1 = (r[j].z & 0xffffu) | (r[j].w << 16);
      uint2 hh; hh.x = h0; hh.y = h1;
      uint2 ll; ll.x = l0; ll.y = l1;
      *(uint2*)&sHg[0][row][c] = hh;
      *(uint2*)&sHg[1][row][c] = ll;
    }
  };

  const f32x4 zero4 = {0.f, 0.f, 0.f, 0.f};

  // ---------------- recurrence (per-wave autonomous stream) ----------------
  for (int t = 0; t < T; ++t){
    // exchange-independent work first: fills the post->poll dependency
    // window of the h(t-1) exchange (hides flag propagation latency).
    float ev[13];
    #pragma unroll
    for (int p = 0; p < 13; ++p){
      int i = lane + p*64;
      ev[p] = (i < 800) ? emb[sTok[g*8 + i/100][t]*E + (i % 100)] : 0.f;
    }
    #pragma unroll
    for (int p = 0; p < 13; ++p){
      int i = lane + p*64;
      if (i < 800){
        int row = i / 100, e = i % 100;
        short hi = f2bf(ev[p]);
        short lo = f2bf(ev[p] - bf2f(hi));
        sEg[0][row][e] = hi; sEg[1][row][e] = lo;
      }
    }
    // x@k0 partial (independent of the exchange)
    f32x4 za = zero4, zb = zero4, zc = zero4, zd = zero4;
    #pragma unroll
    for (int kk = 0; kk < 4; ++kk){
      short8 ah = *(const short8*)&sEg[0][m7][kk*32 + q*8];
      short8 al = *(const short8*)&sEg[1][m7][kk*32 + q*8];
      short8 bh = *(const short8*)&sK0[0][m][kk*32 + q*8];
      short8 bl = *(const short8*)&sK0[1][m][kk*32 + q*8];
      za = MFMA16(ah, bh, za); zb = MFMA16(al, bh, zb);
      zc = MFMA16(ah, bl, zc); zd = MFMA16(al, bl, zd);
    }
    // ---- round A: h0 = tanh(x@k0 + h@rk0 + b0); also z1 = h@rk1 partial
    f32x4 z1a = zero4, z1b = zero4, z1c = zero4, z1d = zero4;
    if (t > 0){
      pollFlags(2*t);                  // all members' h(t-1) posts (this group)
      gather(hRow0);
      #pragma unroll
      for (int kk = 0; kk < 16; ++kk){
        short8 ah  = *(const short8*)&sHg[0][m7][kk*32 + q*8];
        short8 al  = *(const short8*)&sHg[1][m7][kk*32 + q*8];
        short8 b0h = *(const short8*)&sW[0][m][kk*32 + q*8];
        short8 b0l = *(const short8*)&sW[1][m][kk*32 + q*8];
        short8 b1h = *(const short8*)&sW[2][m][kk*32 + q*8];
        short8 b1l = *(const short8*)&sW[3][m][kk*32 + q*8];
        za  = MFMA16(ah, b0h, za);  zb  = MFMA16(al, b0h, zb);
        zc  = MFMA16(ah, b0l, zc);  zd  = MFMA16(al, b0l, zd);
        z1a = MFMA16(ah, b1h, z1a); z1b = MFMA16(al, b1h, z1b);
        z1c = MFMA16(ah, b1l, z1c); z1d = MFMA16(al, b1l, z1d);
      }
    }
    {
      f32x4 z = za; z += zb; z += zc; z += zd;
      if (q < 2){                      // rows 0..7 valid (8-15 are dups)
        #pragma unroll
        for (int r = 0; r < 4; ++r){
          float h0v = fast_tanh(z[r] + sB0[m]);
          short hi = f2bf(h0v);
          short lo = f2bf(h0v - bf2f(hi));
          unsigned pk = ((unsigned)(unsigned short)hi << 16) | (unsigned short)lo;
          h0Row0[(q*4 + r)*U + mem*16 + m] = pk;   // plain store -> XCD L2
        }
      }
      post(2*t + 1);                   // h0 ready (this member, this group)
    }

    // ---- round B: h1 = tanh(h0@k1 + z1 + b1)
    pollFlags(2*t + 1);
    gather(h0Row0);
    #pragma unroll
    for (int kk = 0; kk < 16; ++kk){
      short8 ah = *(const short8*)&sHg[0][m7][kk*32 + q*8];
      short8 al = *(const short8*)&sHg[1][m7][kk*32 + q*8];
      short8 bh = *(const short8*)&sW[4][m][kk*32 + q*8];
      short8 bl = *(const short8*)&sW[5][m][kk*32 + q*8];
      z1a = MFMA16(ah, bh, z1a); z1b = MFMA16(al, bh, z1b);
      z1c = MFMA16(ah, bl, z1c); z1d = MFMA16(al, bl, z1d);
    }
    {
      f32x4 y = z1a; y += z1b; y += z1c; y += z1d;
      if (q < 2){
        #pragma unroll
        for (int r = 0; r < 4; ++r){
          float h1v = fast_tanh(y[r] + sB1[m]);
          short hi = f2bf(h1v);
          short lo = f2bf(h1v - bf2f(hi));
          unsigned pk = ((unsigned)(unsigned short)hi << 16) | (unsigned short)lo;
          hRow0[(q*4 + r)*U + mem*16 + m] = pk;    // plain store -> XCD L2
        }
      }
      post(2*t + 2);                   // h(t) ready (this member, this group)
    }
  }

  // ---------------- epilogue: logits = h@wd + bd ; sigmoid ----------------
  // Each wave of the member-0 block handles its own 8 rows; no barrier.
  if (mem == 0){
    pollFlags(2*T);
    gather(hRow0);
    int row = lane >> 3, seg = lane & 7;
    float acc = 0.f;
    for (int u = seg*64; u < seg*64 + 64; ++u){
      float hv = bf2f(sHg[0][row][u]) + bf2f(sHg[1][row][u]);
      acc += hv * wd[u];
    }
    acc += __shfl_xor(acc, 1);
    acc += __shfl_xor(acc, 2);
    acc += __shfl_xor(acc, 4);
    if (seg == 0){
      float s = acc + bd[0];
      out[cl*16 + g*8 + row] = 1.f / (1.f + __expf(-s));
    }
  }

  // replay hygiene: flush this XCD's dirty L2 exchange lines (one-time cost)
  __threadfence();
}

extern "C" void kernel_launch(void* const* d_in, const int* in_sizes, int n_in,
                              void* d_out, int out_size, void* d_ws, size_t ws_size,
                              hipStream_t stream) {
  const int*   tokens = (const int*)  d_in[0];
  const float* emb    = (const float*)d_in[1];
  const float* k0     = (const float*)d_in[2];
  const float* rk0    = (const float*)d_in[3];
  const float* b0     = (const float*)d_in[4];
  const float* k1     = (const float*)d_in[5];
  const float* rk1    = (const float*)d_in[6];
  const float* b1     = (const float*)d_in[7];
  const float* wd     = (const float*)d_in[8];
  const float* bd     = (const float*)d_in[9];

  // Zero registration counters + flag region (0xAA poison breaks monotonic
  // arith). regCnt@512, flags@4096..36864; exchange data starts at 40960
  // (fully rewritten before first gather — no memset needed there).
  hipMemsetAsync(d_ws, 0, 40960, stream);

  hipLaunchKernelGGL(rnn_kernel, dim3(256), dim3(128), 0, stream,
                     tokens, emb, k0, rk0, b0, k1, rk1, b1, wd, bd,
                     (float*)d_out, (char*)d_ws);
}